// Round 13
// baseline (175.025 us; speedup 1.0000x reference)
//
#include <hip/hip_runtime.h>

#define EDIM   4096
#define NHEAD  32
#define DHEAD  128
#define LCACHE 8191
#define LTOT   8192
#define NSPLIT 1024
#define RPB    8     // rows per split (NSPLIT*RPB == LTOT)
#define NGRP   8     // combine stage-1 groups
#define SPG    128   // splits per group (NSPLIT/NGRP)

#define SCALE 0.08838834764831845f  // 1/sqrt(128)

typedef float __attribute__((ext_vector_type(4))) f32x4;
typedef unsigned short u16;
typedef unsigned short __attribute__((ext_vector_type(4))) u16x4;

__device__ __forceinline__ f32x4 ntload4(const float* p) {
    return __builtin_nontemporal_load((const f32x4*)p);
}
__device__ __forceinline__ f32x4 ld4(const float* p) {
    return *(const f32x4*)p;
}
__device__ __forceinline__ void st4(float* p, f32x4 v) {
    *(f32x4*)p = v;           // PLAIN store: L2 write-back path (fill-proven 7.1 TB/s)
}
__device__ __forceinline__ float dot4(f32x4 a, f32x4 b) {
    return a.x*b.x + a.y*b.y + a.z*b.z + a.w*b.w;
}
__device__ __forceinline__ u16 f2bf(float f) {
    union { float f; unsigned int u; } x; x.f = f;
    unsigned int r = x.u + 0x7fffu + ((x.u >> 16) & 1u);  // RNE
    return (u16)(r >> 16);
}
__device__ __forceinline__ float bf2f(u16 u) {
    union { unsigned int u; float f; } x;
    x.u = ((unsigned int)u) << 16;
    return x.f;
}

// ---------------------------------------------------------------------------
// Kernel 1: q/k/v GEMVs. One 64-lane wave per output row, 4 rows/block.
// grid 3072. Wk/Wv non-temporal loads; Wq temporal (reused by proj).
// ---------------------------------------------------------------------------
__global__ __launch_bounds__(256) void qkv_kernel(
    const float* __restrict__ seq,
    const float* __restrict__ Wq, const float* __restrict__ bq,
    const float* __restrict__ Wk, const float* __restrict__ bk,
    const float* __restrict__ Wv, const float* __restrict__ bv,
    float* __restrict__ q_f, float* __restrict__ out)
{
    int idx  = blockIdx.x * 4 + (threadIdx.x >> 6);
    int lane = threadIdx.x & 63;
    int sel  = idx >> 12;
    int row  = idx & 4095;
    const float* W = sel == 0 ? Wq : (sel == 1 ? Wk : Wv);
    const float* b = sel == 0 ? bq : (sel == 1 ? bk : bv);
    const float* wr = W + (size_t)row * EDIM;

    float sum = 0.f;
#pragma unroll
    for (int i = 0; i < 16; ++i) {
        int c = (i * 64 + lane) * 4;
        f32x4 w = (sel == 0) ? ld4(wr + c) : ntload4(wr + c);
        f32x4 s = ld4(seq + c);
        sum += dot4(w, s);
    }
#pragma unroll
    for (int m = 32; m; m >>= 1) sum += __shfl_xor(sum, m);
    if (lane == 0) {
        float total = sum + b[row];
        if (sel == 0)      q_f[row] = total;
        else if (sel == 1) out[(size_t)EDIM * (1 + LCACHE) + row] = total;
        else               out[(size_t)EDIM * (1 + LTOT + LCACHE) + row] = total;
    }
}

// ---------------------------------------------------------------------------
// Kernel 2: fused KV-copy + flash-decode, one-pass online softmax.
// grid 1024, block 256. NT loads for streaming reads; PLAIN stores for the
// copy-out (L2 write-back aggregation). 2-deep register prefetch, no barriers.
// po partials bf16.
// ---------------------------------------------------------------------------
__global__ __launch_bounds__(256) void fused_kernel(
    const float* __restrict__ kc, const float* __restrict__ vc,
    const float* __restrict__ q_f, float* __restrict__ out,
    float* __restrict__ pm, float* __restrict__ pl, u16* __restrict__ po)
{
    int s  = blockIdx.x;
    int t  = threadIdx.x;
    int g  = t >> 5;
    int r0 = s * RPB;

    float* knew = out + EDIM;
    float* vnew = out + (size_t)EDIM * (1 + LTOT);
    int c0 = t * 4;

    float qr[16];
#pragma unroll
    for (int j = 0; j < 4; ++j) {
        f32x4 v = ld4(q_f + j * 1024 + c0);
        qr[j*4+0] = v.x * SCALE; qr[j*4+1] = v.y * SCALE;
        qr[j*4+2] = v.z * SCALE; qr[j*4+3] = v.w * SCALE;
    }

    float m[4], l[4];
    f32x4 acc[4];
#pragma unroll
    for (int j = 0; j < 4; ++j) {
        m[j] = -1e30f; l[j] = 0.f;
        acc[j] = (f32x4){0.f, 0.f, 0.f, 0.f};
    }

    f32x4 a[4], b[4];
    {
        const float* ksrc = (r0 < LCACHE) ? (kc + (size_t)r0 * EDIM)
                                          : (knew + (size_t)r0 * EDIM);
        const float* vsrc = (r0 < LCACHE) ? (vc + (size_t)r0 * EDIM)
                                          : (vnew + (size_t)r0 * EDIM);
#pragma unroll
        for (int j = 0; j < 4; ++j) a[j] = ntload4(ksrc + j * 1024 + c0);
#pragma unroll
        for (int j = 0; j < 4; ++j) b[j] = ntload4(vsrc + j * 1024 + c0);
    }

    for (int i = 0; i < RPB; ++i) {
        int row = r0 + i;
        f32x4 a2[4], b2[4];
        if (i + 1 < RPB) {
            int nrow = row + 1;
            const float* ksrc = (nrow < LCACHE) ? (kc + (size_t)nrow * EDIM)
                                                : (knew + (size_t)nrow * EDIM);
            const float* vsrc = (nrow < LCACHE) ? (vc + (size_t)nrow * EDIM)
                                                : (vnew + (size_t)nrow * EDIM);
#pragma unroll
            for (int j = 0; j < 4; ++j) a2[j] = ntload4(ksrc + j * 1024 + c0);
#pragma unroll
            for (int j = 0; j < 4; ++j) b2[j] = ntload4(vsrc + j * 1024 + c0);
        }
        if (row < LCACHE) {
            float* kd = knew + (size_t)row * EDIM;
            float* vd = vnew + (size_t)row * EDIM;
#pragma unroll
            for (int j = 0; j < 4; ++j) st4(kd + j * 1024 + c0, a[j]);
#pragma unroll
            for (int j = 0; j < 4; ++j) st4(vd + j * 1024 + c0, b[j]);
        }
        float pd[4];
#pragma unroll
        for (int j = 0; j < 4; ++j) pd[j] = dot4(a[j], ld4(&qr[j*4]));
#pragma unroll
        for (int msk = 1; msk <= 16; msk <<= 1) {
#pragma unroll
            for (int j = 0; j < 4; ++j) pd[j] += __shfl_xor(pd[j], msk);
        }
#pragma unroll
        for (int j = 0; j < 4; ++j) {
            float mn = fmaxf(m[j], pd[j]);
            float r  = __expf(m[j] - mn);
            float p  = __expf(pd[j] - mn);
            l[j] = l[j] * r + p;
            acc[j] = acc[j] * r + p * b[j];
            m[j] = mn;
        }
#pragma unroll
        for (int j = 0; j < 4; ++j) { a[j] = a2[j]; b[j] = b2[j]; }
    }

    int lane32 = t & 31;
    if (lane32 == 0) {
#pragma unroll
        for (int j = 0; j < 4; ++j) {
            int head = j * 8 + g;
            pm[(size_t)head * NSPLIT + s] = m[j];
            pl[(size_t)head * NSPLIT + s] = l[j];
        }
    }
#pragma unroll
    for (int j = 0; j < 4; ++j) {
        int head = j * 8 + g;
        u16x4 pk;
        pk.x = f2bf(acc[j].x); pk.y = f2bf(acc[j].y);
        pk.z = f2bf(acc[j].z); pk.w = f2bf(acc[j].w);
        *(u16x4*)(po + ((size_t)head * NSPLIT + s) * DHEAD + lane32 * 4) = pk;
    }
}

// ---------------------------------------------------------------------------
// Kernel 3: combine stage 1.  grid (NHEAD, NGRP), 256 thr = 8 subgroups
// of 32 lanes; lane owns 4 dims (bf16x4 po reads); subgroup strides splits.
// ---------------------------------------------------------------------------
__global__ __launch_bounds__(256) void combine1_kernel(
    const float* __restrict__ pm, const float* __restrict__ pl,
    const u16* __restrict__ po,
    float* __restrict__ gm, float* __restrict__ gl, float* __restrict__ go)
{
    int h   = blockIdx.x;
    int grp = blockIdx.y;
    int t   = threadIdx.x;
    int sg  = t >> 5;
    int ln  = t & 31;
    int s0  = grp * SPG;

    __shared__ float sm[SPG], sw[SPG];
    __shared__ f32x4 red[8][32];
    __shared__ float redl[8];

    if (t < SPG) {
        sm[t] = pm[(size_t)h * NSPLIT + s0 + t];
        sw[t] = pl[(size_t)h * NSPLIT + s0 + t];
    }
    __syncthreads();

    float M = -1e30f;
#pragma unroll 8
    for (int i = 0; i < SPG; ++i) M = fmaxf(M, sm[i]);

    f32x4 o4 = (f32x4){0.f, 0.f, 0.f, 0.f};
    float L = 0.f;
    for (int i = sg; i < SPG; i += 8) {
        float w = __expf(sm[i] - M);
        u16x4 u = *(const u16x4*)(po + ((size_t)h * NSPLIT + s0 + i) * DHEAD + ln * 4);
        f32x4 v;
        v.x = bf2f(u.x); v.y = bf2f(u.y); v.z = bf2f(u.z); v.w = bf2f(u.w);
        o4 += w * v;
        L += w * sw[i];
    }
    red[sg][ln] = o4;
    if (ln == 0) redl[sg] = L;
    __syncthreads();
    if (sg == 0) {
        f32x4 oo = red[0][ln];
#pragma unroll
        for (int k = 1; k < 8; ++k) oo += red[k][ln];
        *(f32x4*)(go + ((size_t)h * NGRP + grp) * DHEAD + ln * 4) = oo;
        if (ln == 0) {
            float LL = redl[0];
#pragma unroll
            for (int k = 1; k < 8; ++k) LL += redl[k];
            gm[h * NGRP + grp] = M;
            gl[h * NGRP + grp] = LL;
        }
    }
}

// ---------------------------------------------------------------------------
// Kernel 4: proj with inline combine2.  grid 1024, 256 thr (4 waves).
// ---------------------------------------------------------------------------
__global__ __launch_bounds__(256) void proj_kernel(
    const float* __restrict__ gm, const float* __restrict__ gl,
    const float* __restrict__ go, const float* __restrict__ Wq,
    const float* __restrict__ bq, float* __restrict__ out)
{
    int t = threadIdx.x;
    __shared__ float wnorm[NHEAD * NGRP];   // 256
    __shared__ float attn_s[EDIM];          // 16 KB

    // --- inline combine2: per-head softmax-merge weights ---
    {
        float mg = gm[t];                   // t = h*8+g
        float M = mg;
        M = fmaxf(M, __shfl_xor(M, 1));
        M = fmaxf(M, __shfl_xor(M, 2));
        M = fmaxf(M, __shfl_xor(M, 4));
        float w = __expf(mg - M);
        float Lc = w * gl[t];
        Lc += __shfl_xor(Lc, 1);
        Lc += __shfl_xor(Lc, 2);
        Lc += __shfl_xor(Lc, 4);
        wnorm[t] = w / Lc;
    }
    __syncthreads();

    // --- attn vector into LDS: 16 dims per thread ---
#pragma unroll
    for (int i = 0; i < 16; ++i) {
        int d  = i * 256 + t;
        int h  = d >> 7;
        int dd = d & 127;
        float o = 0.f;
#pragma unroll
        for (int g = 0; g < NGRP; ++g)
            o += wnorm[h * NGRP + g] * go[((size_t)h * NGRP + g) * DHEAD + dd];
        attn_s[d] = o;
    }
    __syncthreads();

    // --- GEMV: one wave per output row, 4 rows/block ---
    int row  = blockIdx.x * 4 + (t >> 6);
    int lane = t & 63;
    const float* wr = Wq + (size_t)row * EDIM;
    float sum = 0.f;
#pragma unroll
    for (int i = 0; i < 16; ++i) {
        int c = (i * 64 + lane) * 4;
        sum += dot4(ld4(wr + c), *(const f32x4*)(attn_s + c));
    }
#pragma unroll
    for (int m = 32; m; m >>= 1) sum += __shfl_xor(sum, m);
    if (lane == 0)
        out[row] = sum + bq[row];
}

// ---------------------------------------------------------------------------
extern "C" void kernel_launch(void* const* d_in, const int* in_sizes, int n_in,
                              void* d_out, int out_size, void* d_ws, size_t ws_size,
                              hipStream_t stream)
{
    const float* seq = (const float*)d_in[0];
    const float* kc  = (const float*)d_in[1];
    const float* vc  = (const float*)d_in[2];
    const float* Wq  = (const float*)d_in[3];
    const float* bq  = (const float*)d_in[4];
    const float* Wk  = (const float*)d_in[5];
    const float* bk  = (const float*)d_in[6];
    const float* Wv  = (const float*)d_in[7];
    const float* bv  = (const float*)d_in[8];
    float* out = (float*)d_out;

    float* wsf    = (float*)d_ws;
    float* q_f    = wsf;                        // 4096
    float* pm     = wsf + 4096;                 // 32*1024
    float* pl     = pm + NHEAD * NSPLIT;        // 32*1024
    float* gm     = pl + NHEAD * NSPLIT;        // 32*8
    float* gl     = gm + NHEAD * NGRP;          // 32*8
    float* go     = gl + NHEAD * NGRP;          // 32*8*128
    u16*   po     = (u16*)(go + NHEAD * NGRP * DHEAD);  // 32*1024*128 bf16

    hipLaunchKernelGGL(qkv_kernel, dim3(3072), dim3(256), 0, stream,
                       seq, Wq, bq, Wk, bk, Wv, bv, q_f, out);
    hipLaunchKernelGGL(fused_kernel, dim3(NSPLIT), dim3(256), 0, stream,
                       kc, vc, q_f, out, pm, pl, po);
    hipLaunchKernelGGL(combine1_kernel, dim3(NHEAD, NGRP), dim3(256), 0, stream,
                       pm, pl, po, gm, gl, go);
    hipLaunchKernelGGL(proj_kernel, dim3(1024), dim3(256), 0, stream,
                       gm, gl, go, Wq, bq, out);
}

// Round 14
// 170.701 us; speedup vs baseline: 1.0253x; 1.0253x over previous
//
#include <hip/hip_runtime.h>

#define EDIM   4096
#define NHEAD  32
#define DHEAD  128
#define LCACHE 8191
#define LTOT   8192
#define NSPLIT 1024
#define RPB    8     // rows per split (NSPLIT*RPB == LTOT)
#define NGRP   8     // combine stage-1 groups
#define SPG    128   // splits per group (NSPLIT/NGRP)

#define SCALE 0.08838834764831845f  // 1/sqrt(128)

typedef float __attribute__((ext_vector_type(4))) f32x4;

__device__ __forceinline__ f32x4 ntload4(const float* p) {
    return __builtin_nontemporal_load((const f32x4*)p);
}
__device__ __forceinline__ void ntstore4(float* p, f32x4 v) {
    __builtin_nontemporal_store(v, (f32x4*)p);
}
__device__ __forceinline__ f32x4 ld4(const float* p) {
    return *(const f32x4*)p;
}
__device__ __forceinline__ float dot4(f32x4 a, f32x4 b) {
    return a.x*b.x + a.y*b.y + a.z*b.z + a.w*b.w;
}

// ---------------------------------------------------------------------------
// Kernel 1: q/k/v GEMVs. One 64-lane wave per output row, 4 rows/block.
// grid 3072. Wk/Wv non-temporal loads; Wq temporal (reused by proj via L3).
// ---------------------------------------------------------------------------
__global__ __launch_bounds__(256) void qkv_kernel(
    const float* __restrict__ seq,
    const float* __restrict__ Wq, const float* __restrict__ bq,
    const float* __restrict__ Wk, const float* __restrict__ bk,
    const float* __restrict__ Wv, const float* __restrict__ bv,
    float* __restrict__ q_f, float* __restrict__ out)
{
    int idx  = blockIdx.x * 4 + (threadIdx.x >> 6);
    int lane = threadIdx.x & 63;
    int sel  = idx >> 12;
    int row  = idx & 4095;
    const float* W = sel == 0 ? Wq : (sel == 1 ? Wk : Wv);
    const float* b = sel == 0 ? bq : (sel == 1 ? bk : bv);
    const float* wr = W + (size_t)row * EDIM;

    float sum = 0.f;
#pragma unroll
    for (int i = 0; i < 16; ++i) {
        int c = (i * 64 + lane) * 4;
        f32x4 w = (sel == 0) ? ld4(wr + c) : ntload4(wr + c);
        f32x4 s = ld4(seq + c);
        sum += dot4(w, s);
    }
#pragma unroll
    for (int m = 32; m; m >>= 1) sum += __shfl_xor(sum, m);
    if (lane == 0) {
        float total = sum + b[row];
        if (sel == 0)      q_f[row] = total;
        else if (sel == 1) out[(size_t)EDIM * (1 + LCACHE) + row] = total;
        else               out[(size_t)EDIM * (1 + LTOT + LCACHE) + row] = total;
    }
}

// ---------------------------------------------------------------------------
// Kernel 2: fused KV-copy + flash-decode, one-pass online softmax.
// grid 1024, block 256, __launch_bounds__(256,4): K-only register prefetch
// keeps VGPR < 128 (R8's equivalent phase compiled to 92) -> 4 blocks/CU,
// 16 waves/CU. V loaded directly per row; its latency hides under the
// K-dot + butterfly + TLP. NT loads + NT stores (protect Wq in L3).
// ---------------------------------------------------------------------------
__global__ __launch_bounds__(256, 4) void fused_kernel(
    const float* __restrict__ kc, const float* __restrict__ vc,
    const float* __restrict__ q_f, float* __restrict__ out,
    float* __restrict__ pm, float* __restrict__ pl, float* __restrict__ po)
{
    int s  = blockIdx.x;
    int t  = threadIdx.x;
    int g  = t >> 5;
    int r0 = s * RPB;

    float* knew = out + EDIM;
    float* vnew = out + (size_t)EDIM * (1 + LTOT);
    int c0 = t * 4;

    float qr[16];
#pragma unroll
    for (int j = 0; j < 4; ++j) {
        f32x4 v = ld4(q_f + j * 1024 + c0);
        qr[j*4+0] = v.x * SCALE; qr[j*4+1] = v.y * SCALE;
        qr[j*4+2] = v.z * SCALE; qr[j*4+3] = v.w * SCALE;
    }

    float m[4], l[4];
    f32x4 acc[4];
#pragma unroll
    for (int j = 0; j < 4; ++j) {
        m[j] = -1e30f; l[j] = 0.f;
        acc[j] = (f32x4){0.f, 0.f, 0.f, 0.f};
    }

    // K prologue (r0 <= 8184 < LCACHE always)
    f32x4 a[4];
    {
        const float* ksrc = kc + (size_t)r0 * EDIM;
#pragma unroll
        for (int j = 0; j < 4; ++j) a[j] = ntload4(ksrc + j * 1024 + c0);
    }

    for (int i = 0; i < RPB; ++i) {
        int row = r0 + i;
        bool cached = row < LCACHE;
        // V load for current row (issue ASAP; consumed after butterfly)
        f32x4 b[4];
        {
            const float* vsrc = cached ? (vc + (size_t)row * EDIM)
                                       : (vnew + (size_t)row * EDIM);
#pragma unroll
            for (int j = 0; j < 4; ++j) b[j] = ntload4(vsrc + j * 1024 + c0);
        }
        // K copy-out
        if (cached) {
            float* kd = knew + (size_t)row * EDIM;
#pragma unroll
            for (int j = 0; j < 4; ++j) ntstore4(kd + j * 1024 + c0, a[j]);
        }
        // scores: partial dots + butterfly over 32 lanes
        float pd[4];
#pragma unroll
        for (int j = 0; j < 4; ++j) pd[j] = dot4(a[j], ld4(&qr[j*4]));
#pragma unroll
        for (int msk = 1; msk <= 16; msk <<= 1) {
#pragma unroll
            for (int j = 0; j < 4; ++j) pd[j] += __shfl_xor(pd[j], msk);
        }
        // prefetch next K (reuses a2 -> a)
        f32x4 a2[4];
        if (i + 1 < RPB) {
            int nrow = row + 1;
            const float* ksrc = (nrow < LCACHE)
                ? (kc + (size_t)nrow * EDIM)
                : (knew + (size_t)nrow * EDIM);
#pragma unroll
            for (int j = 0; j < 4; ++j) a2[j] = ntload4(ksrc + j * 1024 + c0);
        }
        // V copy-out
        if (cached) {
            float* vd = vnew + (size_t)row * EDIM;
#pragma unroll
            for (int j = 0; j < 4; ++j) ntstore4(vd + j * 1024 + c0, b[j]);
        }
        // online softmax update per head
#pragma unroll
        for (int j = 0; j < 4; ++j) {
            float mn = fmaxf(m[j], pd[j]);
            float r  = __expf(m[j] - mn);
            float p  = __expf(pd[j] - mn);
            l[j] = l[j] * r + p;
            acc[j] = acc[j] * r + p * b[j];
            m[j] = mn;
        }
#pragma unroll
        for (int j = 0; j < 4; ++j) a[j] = a2[j];
    }

    int lane32 = t & 31;
    if (lane32 == 0) {
#pragma unroll
        for (int j = 0; j < 4; ++j) {
            int head = j * 8 + g;
            pm[(size_t)head * NSPLIT + s] = m[j];
            pl[(size_t)head * NSPLIT + s] = l[j];
        }
    }
#pragma unroll
    for (int j = 0; j < 4; ++j) {
        int head = j * 8 + g;
        ntstore4(po + ((size_t)head * NSPLIT + s) * DHEAD + lane32 * 4, acc[j]);
    }
}

// ---------------------------------------------------------------------------
// Kernel 3: combine stage 1.  grid (NHEAD, NGRP), 256 thr = 8 subgroups
// of 32 lanes; lane owns f32x4 of head dim; subgroup strides splits.
// ---------------------------------------------------------------------------
__global__ __launch_bounds__(256) void combine1_kernel(
    const float* __restrict__ pm, const float* __restrict__ pl,
    const float* __restrict__ po,
    float* __restrict__ gm, float* __restrict__ gl, float* __restrict__ go)
{
    int h   = blockIdx.x;
    int grp = blockIdx.y;
    int t   = threadIdx.x;
    int sg  = t >> 5;
    int ln  = t & 31;
    int s0  = grp * SPG;

    __shared__ float sm[SPG], sw[SPG];
    __shared__ f32x4 red[8][32];
    __shared__ float redl[8];

    if (t < SPG) {
        sm[t] = pm[(size_t)h * NSPLIT + s0 + t];
        sw[t] = pl[(size_t)h * NSPLIT + s0 + t];
    }
    __syncthreads();

    float M = -1e30f;
#pragma unroll 8
    for (int i = 0; i < SPG; ++i) M = fmaxf(M, sm[i]);

    f32x4 o4 = (f32x4){0.f, 0.f, 0.f, 0.f};
    float L = 0.f;
    for (int i = sg; i < SPG; i += 8) {
        float w = __expf(sm[i] - M);
        o4 += w * ld4(po + ((size_t)h * NSPLIT + s0 + i) * DHEAD + ln * 4);
        L += w * sw[i];
    }
    red[sg][ln] = o4;
    if (ln == 0) redl[sg] = L;
    __syncthreads();
    if (sg == 0) {
        f32x4 oo = red[0][ln];
#pragma unroll
        for (int k = 1; k < 8; ++k) oo += red[k][ln];
        *(f32x4*)(go + ((size_t)h * NGRP + grp) * DHEAD + ln * 4) = oo;
        if (ln == 0) {
            float LL = redl[0];
#pragma unroll
            for (int k = 1; k < 8; ++k) LL += redl[k];
            gm[h * NGRP + grp] = M;
            gl[h * NGRP + grp] = LL;
        }
    }
}

// ---------------------------------------------------------------------------
// Kernel 4: combine stage 2.  grid NHEAD, 128 thr: merge NGRP groups.
// ---------------------------------------------------------------------------
__global__ __launch_bounds__(128) void combine2_kernel(
    const float* __restrict__ gm, const float* __restrict__ gl,
    const float* __restrict__ go, float* __restrict__ attn_f)
{
    int h = blockIdx.x;
    int d = threadIdx.x;
    float M = -1e30f;
#pragma unroll
    for (int g = 0; g < NGRP; ++g) M = fmaxf(M, gm[h * NGRP + g]);
    float o = 0.f, L = 0.f;
#pragma unroll
    for (int g = 0; g < NGRP; ++g) {
        float w = __expf(gm[h * NGRP + g] - M);
        o += w * go[((size_t)h * NGRP + g) * DHEAD + d];
        L += w * gl[h * NGRP + g];
    }
    attn_f[h * DHEAD + d] = o / L;
}

// ---------------------------------------------------------------------------
// Kernel 5: output projection. One wave per row, 4 rows/block, grid 1024.
// ---------------------------------------------------------------------------
__global__ __launch_bounds__(256) void proj_kernel(
    const float* __restrict__ attn_f, const float* __restrict__ Wq,
    const float* __restrict__ bq, float* __restrict__ out)
{
    int row  = blockIdx.x * 4 + (threadIdx.x >> 6);
    int lane = threadIdx.x & 63;
    const float* wr = Wq + (size_t)row * EDIM;

    float sum = 0.f;
#pragma unroll
    for (int i = 0; i < 16; ++i) {
        int c = (i * 64 + lane) * 4;
        sum += dot4(ld4(wr + c), ld4(attn_f + c));
    }
#pragma unroll
    for (int m = 32; m; m >>= 1) sum += __shfl_xor(sum, m);
    if (lane == 0)
        out[row] = sum + bq[row];
}

// ---------------------------------------------------------------------------
extern "C" void kernel_launch(void* const* d_in, const int* in_sizes, int n_in,
                              void* d_out, int out_size, void* d_ws, size_t ws_size,
                              hipStream_t stream)
{
    const float* seq = (const float*)d_in[0];
    const float* kc  = (const float*)d_in[1];
    const float* vc  = (const float*)d_in[2];
    const float* Wq  = (const float*)d_in[3];
    const float* bq  = (const float*)d_in[4];
    const float* Wk  = (const float*)d_in[5];
    const float* bk  = (const float*)d_in[6];
    const float* Wv  = (const float*)d_in[7];
    const float* bv  = (const float*)d_in[8];
    float* out = (float*)d_out;

    float* wsf    = (float*)d_ws;
    float* q_f    = wsf;                        // 4096
    float* attn_f = wsf + 4096;                 // 4096
    float* pm     = wsf + 8192;                 // 32*1024
    float* pl     = pm + NHEAD * NSPLIT;        // 32*1024
    float* gm     = pl + NHEAD * NSPLIT;        // 32*8
    float* gl     = gm + NHEAD * NGRP;          // 32*8
    float* go     = gl + NHEAD * NGRP;          // 32*8*128
    float* po     = go + NHEAD * NGRP * DHEAD;  // 32*1024*128

    hipLaunchKernelGGL(qkv_kernel, dim3(3072), dim3(256), 0, stream,
                       seq, Wq, bq, Wk, bk, Wv, bv, q_f, out);
    hipLaunchKernelGGL(fused_kernel, dim3(NSPLIT), dim3(256), 0, stream,
                       kc, vc, q_f, out, pm, pl, po);
    hipLaunchKernelGGL(combine1_kernel, dim3(NHEAD, NGRP), dim3(256), 0, stream,
                       pm, pl, po, gm, gl, go);
    hipLaunchKernelGGL(combine2_kernel, dim3(NHEAD), dim3(128), 0, stream,
                       gm, gl, go, attn_f);
    hipLaunchKernelGGL(proj_kernel, dim3(1024), dim3(256), 0, stream,
                       attn_f, Wq, bq, out);
}